// Round 9
// baseline (184.615 us; speedup 1.0000x reference)
//
#include <hip/hip_runtime.h>

// DOFEN inference fused pipeline — fp32 I/O, MFMA core.
// Shapes: B=1024, NCOL=NCOND=64, NRODT=1024, D=4, NEST=128, NFOREST=100,
//         NHID=128, NCLASS=10.
//
// Round 9: round-8 structure, but atomics back to the d_ws accumulator.
// MEASURED (r8): device atomics into d_out RMW in HBM (fine-grained alloc):
// WRITE_SIZE 6.4->105 MB, FETCH 17->58 MB, k_forest 44->85 us.  Atomics into
// d_ws resolve in cache (r7: 6.4 MB).  So: accp lives in d_ws, k_final adds
// lin2b and scales.  Everything else unchanged from r8 (merged prep kernels,
// bf16 z-tile pad 136 -> 17.4 KB LDS, launch_bounds(256,8)).

#define B_      1024
#define NCOL_   64
#define NCOND_  64
#define NRODT_  1024
#define NEST_   128
#define NFOREST_ 100
#define NHID_   128
#define NCLASS_ 10
#define EPS_    1e-5f

typedef __bf16 bf16_t;
typedef bf16_t bf16x8 __attribute__((ext_vector_type(8)));
typedef float  f32x4  __attribute__((ext_vector_type(4)));

#define MFMA16(a,b,c) __builtin_amdgcn_mfma_f32_16x16x32_bf16(a,b,c,0,0,0)

#define EG_FRAGS   (NFOREST_*4*8*64)   // 204800 frag-rows of 8 bf16
#define W1_FRAGS   (4*8*64)            // 2048
#define L2_FRAGS   (4*64)              // 256
#define ZPAD_      136                 // bf16 z-tile row stride (16B-aligned)

// ---------------------------------------------------------------------------
// K0: x_t[col][b] = x[b][col]  (256 blocks) + accp zero (40 blocks).
// ---------------------------------------------------------------------------
__global__ __launch_bounds__(256) void k_pre(
    const float* __restrict__ x, float* __restrict__ x_t,
    float* __restrict__ accp)
{
    int blk = blockIdx.x, tid = threadIdx.x;
    if (blk < 256) {
        int t = blk * 256 + tid;                  // t = col*1024 + b
        x_t[t] = x[(t & 1023) * NCOL_ + (t >> 10)];
    } else {
        int t = (blk - 256) * 256 + tid;
        if (t < B_ * NCLASS_) accp[t] = 0.f;
    }
}

// ---------------------------------------------------------------------------
// K1: frag tables + rodt.  grid = 800 + 8 + 1 + 1024 = 1833.
// ---------------------------------------------------------------------------
__global__ __launch_bounds__(256) void k_main(
    const float* __restrict__ E,     const int*   __restrict__ swr,
    const float* __restrict__ lin1w, const float* __restrict__ lin2w,
    bf16_t* __restrict__ Eh,  bf16_t* __restrict__ El,
    bf16_t* __restrict__ Wh,  bf16_t* __restrict__ Wl,
    bf16_t* __restrict__ L2h, bf16_t* __restrict__ L2l,
    const float* __restrict__ x_t,  const float* __restrict__ w1,
    const float* __restrict__ b1,   const int*  __restrict__ perm,
    const float* __restrict__ gn1g, const float* __restrict__ gn1b,
    const float* __restrict__ w2a,  const float* __restrict__ b2a,
    const float* __restrict__ gn2g, const float* __restrict__ gn2b,
    const float* __restrict__ w2b,  const float* __restrict__ b2b,
    float* __restrict__ w_t)
{
    int blk = blockIdx.x, tid = threadIdx.x;
    if (blk < 800) {                              // Esel frags: t=(((f*4+kk)*8+nn)*64+lane)
        int t = blk * 256 + tid;
        int lane = t & 63, nn = (t >> 6) & 7, kk = (t >> 9) & 3, f = t >> 11;
        int q = lane >> 4, n = nn * 16 + (lane & 15);
        bf16x8 hi, lo;
#pragma unroll
        for (int j = 0; j < 8; ++j) {
            int e = kk * 32 + q * 8 + j;
            int r = swr[f * NEST_ + e];
            float v = E[r * NHID_ + n];
            bf16_t h = (bf16_t)v;
            hi[j] = h; lo[j] = (bf16_t)(v - (float)h);
        }
        *(bf16x8*)(Eh + (size_t)t * 8) = hi;
        *(bf16x8*)(El + (size_t)t * 8) = lo;
        return;
    }
    if (blk < 808) {                              // lin1w frags: t=(kk*8+nn)*64+lane
        int t = (blk - 800) * 256 + tid;
        int lane = t & 63, nn = (t >> 6) & 7, kk = t >> 9;
        int q = lane >> 4, n = nn * 16 + (lane & 15);
        bf16x8 hi, lo;
#pragma unroll
        for (int j = 0; j < 8; ++j) {
            int k = kk * 32 + q * 8 + j;
            float v = lin1w[k * NHID_ + n];
            bf16_t h = (bf16_t)v;
            hi[j] = h; lo[j] = (bf16_t)(v - (float)h);
        }
        *(bf16x8*)(Wh + t * 8) = hi;
        *(bf16x8*)(Wl + t * 8) = lo;
        return;
    }
    if (blk == 808) {                             // lin2w frags (N pad 16): t=kk*64+lane
        int t = tid;
        int lane = t & 63, kk = t >> 6;
        int q = lane >> 4, n = lane & 15;
        bf16x8 hi, lo;
#pragma unroll
        for (int j = 0; j < 8; ++j) {
            int k = kk * 32 + q * 8 + j;
            float v = (n < NCLASS_) ? lin2w[k * NCLASS_ + n] : 0.f;
            bf16_t h = (bf16_t)v;
            hi[j] = h; lo[j] = (bf16_t)(v - (float)h);
        }
        *(bf16x8*)(L2h + t * 8) = hi;
        *(bf16x8*)(L2l + t * 8) = lo;
        return;
    }

    // ---- rodt: one g per block; thread handles 4 b's ----
    int g  = blk - 809;
    int bq = tid * 4;

    int4 p4 = ((const int4*)perm)[g];
    int col[4]  = { p4.x & 63, p4.y & 63, p4.z & 63, p4.w & 63 };
    int cond[4] = { p4.x >> 6, p4.y >> 6, p4.z >> 6, p4.w >> 6 };
    float w1v[4], b1v[4];
#pragma unroll
    for (int j = 0; j < 4; ++j) {
        w1v[j] = w1[col[j] * NCOND_ + cond[j]];
        b1v[j] = b1[col[j] * NCOND_ + cond[j]];
    }
    float4 g1  = ((const float4*)gn1g)[g];
    float4 o1  = ((const float4*)gn1b)[g];
    float4 ba  = ((const float4*)b2a)[g];
    float4 g2  = ((const float4*)gn2g)[g];
    float4 o2  = ((const float4*)gn2b)[g];
    float4 wb4 = ((const float4*)w2b)[g];
    float  bb  = b2b[g];
    float4 wa[4];
    const float4* w2a4 = (const float4*)w2a;
#pragma unroll
    for (int i = 0; i < 4; ++i) wa[i] = w2a4[g * 4 + i];

    float xv[4][4];
#pragma unroll
    for (int j = 0; j < 4; ++j) {
        float4 t = *(const float4*)&x_t[col[j] * B_ + bq];
        xv[j][0] = t.x; xv[j][1] = t.y; xv[j][2] = t.z; xv[j][3] = t.w;
    }

    float outv[4];
#pragma unroll
    for (int bi = 0; bi < 4; ++bi) {
        float v[4];
#pragma unroll
        for (int j = 0; j < 4; ++j) {
            float t = xv[j][bi] * w1v[j] + b1v[j];
            v[j] = 1.0f / (1.0f + __expf(-t));
        }
        float mu = (v[0] + v[1] + v[2] + v[3]) * 0.25f;
        float var = 0.f;
#pragma unroll
        for (int j = 0; j < 4; ++j) { float d = v[j] - mu; var += d * d; }
        var *= 0.25f;
        float rs = rsqrtf(var + EPS_);
        float h[4];
        h[0] = (v[0] - mu) * rs * g1.x + o1.x;
        h[1] = (v[1] - mu) * rs * g1.y + o1.y;
        h[2] = (v[2] - mu) * rs * g1.z + o1.z;
        h[3] = (v[3] - mu) * rs * g1.w + o1.w;

        float4 a = ba;
#pragma unroll
        for (int i = 0; i < 4; ++i) {
            a.x += h[i] * wa[i].x; a.y += h[i] * wa[i].y;
            a.z += h[i] * wa[i].z; a.w += h[i] * wa[i].w;
        }
        float t2[4];
        t2[0] = fmaxf(a.x, 0.f); t2[1] = fmaxf(a.y, 0.f);
        t2[2] = fmaxf(a.z, 0.f); t2[3] = fmaxf(a.w, 0.f);

        float mu2 = (t2[0] + t2[1] + t2[2] + t2[3]) * 0.25f;
        float var2 = 0.f;
#pragma unroll
        for (int j = 0; j < 4; ++j) { float d = t2[j] - mu2; var2 += d * d; }
        var2 *= 0.25f;
        float rs2 = rsqrtf(var2 + EPS_);

        float wvv = bb;
        wvv += ((t2[0] - mu2) * rs2 * g2.x + o2.x) * wb4.x;
        wvv += ((t2[1] - mu2) * rs2 * g2.y + o2.y) * wb4.y;
        wvv += ((t2[2] - mu2) * rs2 * g2.z + o2.z) * wb4.z;
        wvv += ((t2[3] - mu2) * rs2 * g2.w + o2.w) * wb4.w;
        outv[bi] = wvv;
    }
    *(float4*)&w_t[(size_t)g * B_ + bq] = make_float4(outv[0], outv[1], outv[2], outv[3]);
}

// ---------------------------------------------------------------------------
// K2: block=(f, 64 rows), 4 waves, wave = m-tile (16 rows) x all 8 n-tiles.
// Barrier-free; per-wave 16xZPAD bf16 z-tile.  lane: q=lane>>4, mc=lane&15.
// A: m=mc, k=q*8+j(+32kk).  C: row=q*4+reg, col=nn*16+mc.
// Atomics into WORKSPACE accp (cache-resolved; d_out atomics RMW in HBM).
// ---------------------------------------------------------------------------
__global__ __launch_bounds__(256, 8) void k_forest(
    const float*  __restrict__ w_t, const int* __restrict__ swr,
    const bf16_t* __restrict__ Eh,  const bf16_t* __restrict__ El,
    const bf16_t* __restrict__ Wh,  const bf16_t* __restrict__ Wl,
    const bf16_t* __restrict__ L2h, const bf16_t* __restrict__ L2l,
    const float* __restrict__ ln1g, const float* __restrict__ ln1b,
    const float* __restrict__ lin1b,
    const float* __restrict__ ln2g, const float* __restrict__ ln2b,
    float* __restrict__ accp)
{
    __shared__ bf16_t zsh[4][16 * ZPAD_];   // per-wave bf16 z tile

    int tid  = threadIdx.x;
    int wid  = tid >> 6;
    int lane = tid & 63;
    int q    = lane >> 4;
    int mc   = lane & 15;

    int n    = blockIdx.x;
    int swiz = (n & 7) * 200 + (n >> 3);  // co-locate same-f blocks per XCD
    int f    = swiz >> 4;
    int bt   = swiz & 15;
    int b0   = bt * 64 + wid * 16;        // this wave's first batch row

    const int* swrf = swr + f * NEST_;
    bf16_t* zw = zsh[wid];

    // ---- softmax in A-frag lanes: ws[m=mc][e=kk*32+q*8+j] ----
    float ex[4][8];
    float mx = -1e30f;
#pragma unroll
    for (int kk = 0; kk < 4; ++kk) {
        int4 r0 = *(const int4*)(swrf + kk * 32 + q * 8);
        int4 r1 = *(const int4*)(swrf + kk * 32 + q * 8 + 4);
        int rr[8] = { r0.x, r0.y, r0.z, r0.w, r1.x, r1.y, r1.z, r1.w };
#pragma unroll
        for (int j = 0; j < 8; ++j) {
            float v = w_t[rr[j] * B_ + b0 + mc];
            ex[kk][j] = v;
            mx = fmaxf(mx, v);
        }
    }
    mx = fmaxf(mx, __shfl_xor(mx, 16));
    mx = fmaxf(mx, __shfl_xor(mx, 32));
    float s = 0.f;
#pragma unroll
    for (int kk = 0; kk < 4; ++kk)
#pragma unroll
        for (int j = 0; j < 8; ++j) { ex[kk][j] = __expf(ex[kk][j] - mx); s += ex[kk][j]; }
    s += __shfl_xor(s, 16);
    s += __shfl_xor(s, 32);
    float inv = 1.f / s;

    bf16x8 afr[4];
#pragma unroll
    for (int kk = 0; kk < 4; ++kk)
#pragma unroll
        for (int j = 0; j < 8; ++j) afr[kk][j] = (bf16_t)(ex[kk][j] * inv);

    // ---- F-GEMM: all 8 n-tiles, K=128, B split hi/lo ----
    f32x4 accF[8];
#pragma unroll
    for (int nn = 0; nn < 8; ++nn) accF[nn] = (f32x4){0.f, 0.f, 0.f, 0.f};
    const bf16x8* EHf = (const bf16x8*)Eh;
    const bf16x8* ELf = (const bf16x8*)El;
#pragma unroll
    for (int kk = 0; kk < 4; ++kk) {
        size_t bi = (size_t)(f * 4 + kk) * 8;
#pragma unroll
        for (int nn = 0; nn < 8; ++nn) {
            bf16x8 bh = EHf[(bi + nn) * 64 + lane];
            bf16x8 bl = ELf[(bi + nn) * 64 + lane];
            accF[nn] = MFMA16(afr[kk], bh, accF[nn]);
            accF[nn] = MFMA16(afr[kk], bl, accF[nn]);
        }
    }

    // ---- LayerNorm 1 (wave-internal): rows q*4+reg ----
    float mu[4], rs[4];
#pragma unroll
    for (int reg = 0; reg < 4; ++reg) {
        float ps = 0.f, pq = 0.f;
#pragma unroll
        for (int nn = 0; nn < 8; ++nn) { float v = accF[nn][reg]; ps += v; pq += v * v; }
#pragma unroll
        for (int o = 1; o <= 8; o <<= 1) { ps += __shfl_xor(ps, o); pq += __shfl_xor(pq, o); }
        float m_ = ps * (1.f / NHID_);
        mu[reg] = m_;
        rs[reg] = rsqrtf(pq * (1.f / NHID_) - m_ * m_ + EPS_);
    }
#pragma unroll
    for (int nn = 0; nn < 8; ++nn) {
        int c = nn * 16 + mc;
        float gv = ln1g[c], bv = ln1b[c];
#pragma unroll
        for (int reg = 0; reg < 4; ++reg)
            zw[(q * 4 + reg) * ZPAD_ + c] =
                (bf16_t)((accF[nn][reg] - mu[reg]) * rs[reg] * gv + bv);
    }

    // ---- lin1 GEMM: A straight from bf16 z-tile, B = Wh/Wl ----
    bf16x8 a2[4];
#pragma unroll
    for (int kk = 0; kk < 4; ++kk)
        a2[kk] = *(const bf16x8*)&zw[mc * ZPAD_ + kk * 32 + q * 8];
    f32x4 accA[8];
#pragma unroll
    for (int nn = 0; nn < 8; ++nn) accA[nn] = (f32x4){0.f, 0.f, 0.f, 0.f};
    const bf16x8* WHf = (const bf16x8*)Wh;
    const bf16x8* WLf = (const bf16x8*)Wl;
#pragma unroll
    for (int kk = 0; kk < 4; ++kk) {
#pragma unroll
        for (int nn = 0; nn < 8; ++nn) {
            bf16x8 bh = WHf[(kk * 8 + nn) * 64 + lane];
            bf16x8 bl = WLf[(kk * 8 + nn) * 64 + lane];
            accA[nn] = MFMA16(a2[kk], bh, accA[nn]);
            accA[nn] = MFMA16(a2[kk], bl, accA[nn]);
        }
    }

    // ---- bias + ReLU + LayerNorm 2 (wave-internal) ----
#pragma unroll
    for (int nn = 0; nn < 8; ++nn) {
        float bv = lin1b[nn * 16 + mc];
#pragma unroll
        for (int reg = 0; reg < 4; ++reg)
            accA[nn][reg] = fmaxf(accA[nn][reg] + bv, 0.f);
    }
    float mu2[4], rs2[4];
#pragma unroll
    for (int reg = 0; reg < 4; ++reg) {
        float ps = 0.f, pq = 0.f;
#pragma unroll
        for (int nn = 0; nn < 8; ++nn) { float v = accA[nn][reg]; ps += v; pq += v * v; }
#pragma unroll
        for (int o = 1; o <= 8; o <<= 1) { ps += __shfl_xor(ps, o); pq += __shfl_xor(pq, o); }
        float m_ = ps * (1.f / NHID_);
        mu2[reg] = m_;
        rs2[reg] = rsqrtf(pq * (1.f / NHID_) - m_ * m_ + EPS_);
    }
#pragma unroll
    for (int nn = 0; nn < 8; ++nn) {
        int c = nn * 16 + mc;
        float gv = ln2g[c], bv = ln2b[c];
#pragma unroll
        for (int reg = 0; reg < 4; ++reg)
            zw[(q * 4 + reg) * ZPAD_ + c] =
                (bf16_t)((accA[nn][reg] - mu2[reg]) * rs2[reg] * gv + bv);
    }

    // ---- lin2: 16x128 @ 128x16(pad); accumulate into workspace accp ----
    f32x4 accO = {0.f, 0.f, 0.f, 0.f};
    const bf16x8* LHf = (const bf16x8*)L2h;
    const bf16x8* LLf = (const bf16x8*)L2l;
#pragma unroll
    for (int kk = 0; kk < 4; ++kk) {
        bf16x8 a3 = *(const bf16x8*)&zw[mc * ZPAD_ + kk * 32 + q * 8];
        accO = MFMA16(a3, LHf[kk * 64 + lane], accO);
        accO = MFMA16(a3, LLf[kk * 64 + lane], accO);
    }
    if (mc < NCLASS_) {
#pragma unroll
        for (int reg = 0; reg < 4; ++reg)
            atomicAdd(&accp[(b0 + q * 4 + reg) * NCLASS_ + mc], accO[reg]);
    }
}

// ---------------------------------------------------------------------------
// K3: out = accp/NFOREST + lin2_b
// ---------------------------------------------------------------------------
__global__ __launch_bounds__(256) void k_final(
    const float* __restrict__ accp, const float* __restrict__ lin2b,
    float* __restrict__ out)
{
    int i = blockIdx.x * 256 + threadIdx.x;
    if (i < B_ * NCLASS_) {
        int c = i % NCLASS_;
        out[i] = accp[i] * (1.f / NFOREST_) + lin2b[c];
    }
}

// ---------------------------------------------------------------------------
extern "C" void kernel_launch(void* const* d_in, const int* in_sizes, int n_in,
                              void* d_out, int out_size, void* d_ws, size_t ws_size,
                              hipStream_t stream)
{
    const float* x     = (const float*)d_in[0];
    const float* w1    = (const float*)d_in[1];
    const float* b1    = (const float*)d_in[2];
    const int*   perm  = (const int*)  d_in[3];
    const float* gn1g  = (const float*)d_in[4];
    const float* gn1b  = (const float*)d_in[5];
    const float* w2a   = (const float*)d_in[6];
    const float* b2a   = (const float*)d_in[7];
    const float* gn2g  = (const float*)d_in[8];
    const float* gn2b  = (const float*)d_in[9];
    const float* w2b   = (const float*)d_in[10];
    const float* b2b   = (const float*)d_in[11];
    const float* E     = (const float*)d_in[12];
    const int*   swr   = (const int*)  d_in[13];
    const float* ln1g  = (const float*)d_in[14];
    const float* ln1b  = (const float*)d_in[15];
    const float* lin1w = (const float*)d_in[16];
    const float* lin1b = (const float*)d_in[17];
    const float* ln2g  = (const float*)d_in[18];
    const float* ln2b  = (const float*)d_in[19];
    const float* lin2w = (const float*)d_in[20];
    const float* lin2b = (const float*)d_in[21];

    char* base = (char*)d_ws;
    float*  w_t  = (float*)base;                                    // 4 MB
    float*  x_t  = (float*)(base + 4u * 1024 * 1024);               // 256 KB
    float*  accp = (float*)(base + 4u * 1024 * 1024 + 256 * 1024);  // 40 KB (64K slot)
    bf16_t* Eh   = (bf16_t*)(base + 4u * 1024 * 1024 + 256 * 1024 + 64 * 1024);
    bf16_t* El   = Eh  + (size_t)EG_FRAGS * 8;
    bf16_t* Wh   = El  + (size_t)EG_FRAGS * 8;
    bf16_t* Wl   = Wh  + (size_t)W1_FRAGS * 8;
    bf16_t* L2h  = Wl  + (size_t)W1_FRAGS * 8;
    bf16_t* L2l  = L2h + (size_t)L2_FRAGS * 8;

    float* outp = (float*)d_out;

    k_pre<<<296, 256, 0, stream>>>(x, x_t, accp);

    k_main<<<1833, 256, 0, stream>>>(E, swr, lin1w, lin2w,
                                     Eh, El, Wh, Wl, L2h, L2l,
                                     x_t, w1, b1, perm, gn1g, gn1b,
                                     w2a, b2a, gn2g, gn2b, w2b, b2b, w_t);

    k_forest<<<NFOREST_ * 16, 256, 0, stream>>>(
        w_t, swr, Eh, El, Wh, Wl, L2h, L2l,
        ln1g, ln1b, lin1b, ln2g, ln2b, accp);

    k_final<<<(B_ * NCLASS_ + 255) / 256, 256, 0, stream>>>(
        accp, lin2b, outp);
}

// Round 10
// 150.967 us; speedup vs baseline: 1.2229x; 1.2229x over previous
//
#include <hip/hip_runtime.h>

// DOFEN inference fused pipeline — fp32 I/O, MFMA core.
// Shapes: B=1024, NCOL=NCOND=64, NRODT=1024, D=4, NEST=128, NFOREST=100,
//         NHID=128, NCLASS=10.
//
// Round 10: fix the r8/r9 L2-thrash (measured: at ~9 blocks/CU each XCD's
// whole 200-block queue is live -> 12.5 forests x 640KB = 8MB > 4MB L2 ->
// FETCH 58MB / WRITE 105MB of atomic-line ping-pong).  Two levers:
//  (1) w_t stored bf16 -> per-forest footprint 640->384 KB;
//  (2) LDS sized to 31744B (ZPAD 248) -> exactly 5 blocks/CU -> ~10 forests
//      live x 384KB = 3.8MB <= L2.  Keeps occupancy ~2x r7 without thrash.
// Atomics stay in d_ws accp (cache-resolved); k_final adds bias/mean.

#define B_      1024
#define NCOL_   64
#define NCOND_  64
#define NRODT_  1024
#define NEST_   128
#define NFOREST_ 100
#define NHID_   128
#define NCLASS_ 10
#define EPS_    1e-5f

typedef __bf16 bf16_t;
typedef bf16_t bf16x8 __attribute__((ext_vector_type(8)));
typedef bf16_t bf16x4 __attribute__((ext_vector_type(4)));
typedef float  f32x4  __attribute__((ext_vector_type(4)));

#define MFMA16(a,b,c) __builtin_amdgcn_mfma_f32_16x16x32_bf16(a,b,c,0,0,0)

#define EG_FRAGS   (NFOREST_*4*8*64)   // 204800 frag-rows of 8 bf16
#define W1_FRAGS   (4*8*64)            // 2048
#define L2_FRAGS   (4*64)              // 256
#define ZPAD_      248                 // bf16 z-tile row stride: LDS 31744B
                                       // -> exactly 5 blocks/CU (occupancy cap)

// ---------------------------------------------------------------------------
// K0: x_t[col][b] = x[b][col]  (256 blocks) + accp zero (40 blocks).
// ---------------------------------------------------------------------------
__global__ __launch_bounds__(256) void k_pre(
    const float* __restrict__ x, float* __restrict__ x_t,
    float* __restrict__ accp)
{
    int blk = blockIdx.x, tid = threadIdx.x;
    if (blk < 256) {
        int t = blk * 256 + tid;                  // t = col*1024 + b
        x_t[t] = x[(t & 1023) * NCOL_ + (t >> 10)];
    } else {
        int t = (blk - 256) * 256 + tid;
        if (t < B_ * NCLASS_) accp[t] = 0.f;
    }
}

// ---------------------------------------------------------------------------
// K1: frag tables + rodt (w_t written bf16).  grid = 800+8+1+1024 = 1833.
// ---------------------------------------------------------------------------
__global__ __launch_bounds__(256) void k_main(
    const float* __restrict__ E,     const int*   __restrict__ swr,
    const float* __restrict__ lin1w, const float* __restrict__ lin2w,
    bf16_t* __restrict__ Eh,  bf16_t* __restrict__ El,
    bf16_t* __restrict__ Wh,  bf16_t* __restrict__ Wl,
    bf16_t* __restrict__ L2h, bf16_t* __restrict__ L2l,
    const float* __restrict__ x_t,  const float* __restrict__ w1,
    const float* __restrict__ b1,   const int*  __restrict__ perm,
    const float* __restrict__ gn1g, const float* __restrict__ gn1b,
    const float* __restrict__ w2a,  const float* __restrict__ b2a,
    const float* __restrict__ gn2g, const float* __restrict__ gn2b,
    const float* __restrict__ w2b,  const float* __restrict__ b2b,
    bf16_t* __restrict__ w_t)
{
    int blk = blockIdx.x, tid = threadIdx.x;
    if (blk < 800) {                              // Esel frags: t=(((f*4+kk)*8+nn)*64+lane)
        int t = blk * 256 + tid;
        int lane = t & 63, nn = (t >> 6) & 7, kk = (t >> 9) & 3, f = t >> 11;
        int q = lane >> 4, n = nn * 16 + (lane & 15);
        bf16x8 hi, lo;
#pragma unroll
        for (int j = 0; j < 8; ++j) {
            int e = kk * 32 + q * 8 + j;
            int r = swr[f * NEST_ + e];
            float v = E[r * NHID_ + n];
            bf16_t h = (bf16_t)v;
            hi[j] = h; lo[j] = (bf16_t)(v - (float)h);
        }
        *(bf16x8*)(Eh + (size_t)t * 8) = hi;
        *(bf16x8*)(El + (size_t)t * 8) = lo;
        return;
    }
    if (blk < 808) {                              // lin1w frags: t=(kk*8+nn)*64+lane
        int t = (blk - 800) * 256 + tid;
        int lane = t & 63, nn = (t >> 6) & 7, kk = t >> 9;
        int q = lane >> 4, n = nn * 16 + (lane & 15);
        bf16x8 hi, lo;
#pragma unroll
        for (int j = 0; j < 8; ++j) {
            int k = kk * 32 + q * 8 + j;
            float v = lin1w[k * NHID_ + n];
            bf16_t h = (bf16_t)v;
            hi[j] = h; lo[j] = (bf16_t)(v - (float)h);
        }
        *(bf16x8*)(Wh + t * 8) = hi;
        *(bf16x8*)(Wl + t * 8) = lo;
        return;
    }
    if (blk == 808) {                             // lin2w frags (N pad 16): t=kk*64+lane
        int t = tid;
        int lane = t & 63, kk = t >> 6;
        int q = lane >> 4, n = lane & 15;
        bf16x8 hi, lo;
#pragma unroll
        for (int j = 0; j < 8; ++j) {
            int k = kk * 32 + q * 8 + j;
            float v = (n < NCLASS_) ? lin2w[k * NCLASS_ + n] : 0.f;
            bf16_t h = (bf16_t)v;
            hi[j] = h; lo[j] = (bf16_t)(v - (float)h);
        }
        *(bf16x8*)(L2h + t * 8) = hi;
        *(bf16x8*)(L2l + t * 8) = lo;
        return;
    }

    // ---- rodt: one g per block; thread handles 4 b's ----
    int g  = blk - 809;
    int bq = tid * 4;

    int4 p4 = ((const int4*)perm)[g];
    int col[4]  = { p4.x & 63, p4.y & 63, p4.z & 63, p4.w & 63 };
    int cond[4] = { p4.x >> 6, p4.y >> 6, p4.z >> 6, p4.w >> 6 };
    float w1v[4], b1v[4];
#pragma unroll
    for (int j = 0; j < 4; ++j) {
        w1v[j] = w1[col[j] * NCOND_ + cond[j]];
        b1v[j] = b1[col[j] * NCOND_ + cond[j]];
    }
    float4 g1  = ((const float4*)gn1g)[g];
    float4 o1  = ((const float4*)gn1b)[g];
    float4 ba  = ((const float4*)b2a)[g];
    float4 g2  = ((const float4*)gn2g)[g];
    float4 o2  = ((const float4*)gn2b)[g];
    float4 wb4 = ((const float4*)w2b)[g];
    float  bb  = b2b[g];
    float4 wa[4];
    const float4* w2a4 = (const float4*)w2a;
#pragma unroll
    for (int i = 0; i < 4; ++i) wa[i] = w2a4[g * 4 + i];

    float xv[4][4];
#pragma unroll
    for (int j = 0; j < 4; ++j) {
        float4 t = *(const float4*)&x_t[col[j] * B_ + bq];
        xv[j][0] = t.x; xv[j][1] = t.y; xv[j][2] = t.z; xv[j][3] = t.w;
    }

    bf16x4 outv;
#pragma unroll
    for (int bi = 0; bi < 4; ++bi) {
        float v[4];
#pragma unroll
        for (int j = 0; j < 4; ++j) {
            float t = xv[j][bi] * w1v[j] + b1v[j];
            v[j] = 1.0f / (1.0f + __expf(-t));
        }
        float mu = (v[0] + v[1] + v[2] + v[3]) * 0.25f;
        float var = 0.f;
#pragma unroll
        for (int j = 0; j < 4; ++j) { float d = v[j] - mu; var += d * d; }
        var *= 0.25f;
        float rs = rsqrtf(var + EPS_);
        float h[4];
        h[0] = (v[0] - mu) * rs * g1.x + o1.x;
        h[1] = (v[1] - mu) * rs * g1.y + o1.y;
        h[2] = (v[2] - mu) * rs * g1.z + o1.z;
        h[3] = (v[3] - mu) * rs * g1.w + o1.w;

        float4 a = ba;
#pragma unroll
        for (int i = 0; i < 4; ++i) {
            a.x += h[i] * wa[i].x; a.y += h[i] * wa[i].y;
            a.z += h[i] * wa[i].z; a.w += h[i] * wa[i].w;
        }
        float t2[4];
        t2[0] = fmaxf(a.x, 0.f); t2[1] = fmaxf(a.y, 0.f);
        t2[2] = fmaxf(a.z, 0.f); t2[3] = fmaxf(a.w, 0.f);

        float mu2 = (t2[0] + t2[1] + t2[2] + t2[3]) * 0.25f;
        float var2 = 0.f;
#pragma unroll
        for (int j = 0; j < 4; ++j) { float d = t2[j] - mu2; var2 += d * d; }
        var2 *= 0.25f;
        float rs2 = rsqrtf(var2 + EPS_);

        float wvv = bb;
        wvv += ((t2[0] - mu2) * rs2 * g2.x + o2.x) * wb4.x;
        wvv += ((t2[1] - mu2) * rs2 * g2.y + o2.y) * wb4.y;
        wvv += ((t2[2] - mu2) * rs2 * g2.z + o2.z) * wb4.z;
        wvv += ((t2[3] - mu2) * rs2 * g2.w + o2.w) * wb4.w;
        outv[bi] = (bf16_t)wvv;
    }
    *(bf16x4*)&w_t[(size_t)g * B_ + bq] = outv;
}

// ---------------------------------------------------------------------------
// K2: block=(f, 64 rows), 4 waves, wave = m-tile (16 rows) x all 8 n-tiles.
// Barrier-free; per-wave 16xZPAD bf16 z-tile (LDS sized for 5 blocks/CU).
// lane: q=lane>>4, mc=lane&15.  A: m=mc, k=q*8+j(+32kk).  C: row=q*4+reg,
// col=nn*16+mc.
// ---------------------------------------------------------------------------
__global__ __launch_bounds__(256, 5) void k_forest(
    const bf16_t* __restrict__ w_t, const int* __restrict__ swr,
    const bf16_t* __restrict__ Eh,  const bf16_t* __restrict__ El,
    const bf16_t* __restrict__ Wh,  const bf16_t* __restrict__ Wl,
    const bf16_t* __restrict__ L2h, const bf16_t* __restrict__ L2l,
    const float* __restrict__ ln1g, const float* __restrict__ ln1b,
    const float* __restrict__ lin1b,
    const float* __restrict__ ln2g, const float* __restrict__ ln2b,
    float* __restrict__ accp)
{
    __shared__ bf16_t zsh[4][16 * ZPAD_];   // 31744 B -> 5 blocks/CU

    int tid  = threadIdx.x;
    int wid  = tid >> 6;
    int lane = tid & 63;
    int q    = lane >> 4;
    int mc   = lane & 15;

    int n    = blockIdx.x;
    int swiz = (n & 7) * 200 + (n >> 3);  // same-f blocks consecutive per XCD
    int f    = swiz >> 4;
    int bt   = swiz & 15;
    int b0   = bt * 64 + wid * 16;        // this wave's first batch row

    const int* swrf = swr + f * NEST_;
    bf16_t* zw = zsh[wid];

    // ---- softmax in A-frag lanes: ws[m=mc][e=kk*32+q*8+j] ----
    float ex[4][8];
    float mx = -1e30f;
#pragma unroll
    for (int kk = 0; kk < 4; ++kk) {
        int4 r0 = *(const int4*)(swrf + kk * 32 + q * 8);
        int4 r1 = *(const int4*)(swrf + kk * 32 + q * 8 + 4);
        int rr[8] = { r0.x, r0.y, r0.z, r0.w, r1.x, r1.y, r1.z, r1.w };
#pragma unroll
        for (int j = 0; j < 8; ++j) {
            float v = (float)w_t[rr[j] * B_ + b0 + mc];
            ex[kk][j] = v;
            mx = fmaxf(mx, v);
        }
    }
    mx = fmaxf(mx, __shfl_xor(mx, 16));
    mx = fmaxf(mx, __shfl_xor(mx, 32));
    float s = 0.f;
#pragma unroll
    for (int kk = 0; kk < 4; ++kk)
#pragma unroll
        for (int j = 0; j < 8; ++j) { ex[kk][j] = __expf(ex[kk][j] - mx); s += ex[kk][j]; }
    s += __shfl_xor(s, 16);
    s += __shfl_xor(s, 32);
    float inv = 1.f / s;

    bf16x8 afr[4];
#pragma unroll
    for (int kk = 0; kk < 4; ++kk)
#pragma unroll
        for (int j = 0; j < 8; ++j) afr[kk][j] = (bf16_t)(ex[kk][j] * inv);

    // ---- F-GEMM: all 8 n-tiles, K=128, B split hi/lo ----
    f32x4 accF[8];
#pragma unroll
    for (int nn = 0; nn < 8; ++nn) accF[nn] = (f32x4){0.f, 0.f, 0.f, 0.f};
    const bf16x8* EHf = (const bf16x8*)Eh;
    const bf16x8* ELf = (const bf16x8*)El;
#pragma unroll
    for (int kk = 0; kk < 4; ++kk) {
        size_t bi = (size_t)(f * 4 + kk) * 8;
#pragma unroll
        for (int nn = 0; nn < 8; ++nn) {
            bf16x8 bh = EHf[(bi + nn) * 64 + lane];
            bf16x8 bl = ELf[(bi + nn) * 64 + lane];
            accF[nn] = MFMA16(afr[kk], bh, accF[nn]);
            accF[nn] = MFMA16(afr[kk], bl, accF[nn]);
        }
    }

    // ---- LayerNorm 1 (wave-internal): rows q*4+reg ----
    float mu[4], rs[4];
#pragma unroll
    for (int reg = 0; reg < 4; ++reg) {
        float ps = 0.f, pq = 0.f;
#pragma unroll
        for (int nn = 0; nn < 8; ++nn) { float v = accF[nn][reg]; ps += v; pq += v * v; }
#pragma unroll
        for (int o = 1; o <= 8; o <<= 1) { ps += __shfl_xor(ps, o); pq += __shfl_xor(pq, o); }
        float m_ = ps * (1.f / NHID_);
        mu[reg] = m_;
        rs[reg] = rsqrtf(pq * (1.f / NHID_) - m_ * m_ + EPS_);
    }
#pragma unroll
    for (int nn = 0; nn < 8; ++nn) {
        int c = nn * 16 + mc;
        float gv = ln1g[c], bv = ln1b[c];
#pragma unroll
        for (int reg = 0; reg < 4; ++reg)
            zw[(q * 4 + reg) * ZPAD_ + c] =
                (bf16_t)((accF[nn][reg] - mu[reg]) * rs[reg] * gv + bv);
    }

    // ---- lin1 GEMM: A straight from bf16 z-tile, B = Wh/Wl ----
    bf16x8 a2[4];
#pragma unroll
    for (int kk = 0; kk < 4; ++kk)
        a2[kk] = *(const bf16x8*)&zw[mc * ZPAD_ + kk * 32 + q * 8];
    f32x4 accA[8];
#pragma unroll
    for (int nn = 0; nn < 8; ++nn) accA[nn] = (f32x4){0.f, 0.f, 0.f, 0.f};
    const bf16x8* WHf = (const bf16x8*)Wh;
    const bf16x8* WLf = (const bf16x8*)Wl;
#pragma unroll
    for (int kk = 0; kk < 4; ++kk) {
#pragma unroll
        for (int nn = 0; nn < 8; ++nn) {
            bf16x8 bh = WHf[(kk * 8 + nn) * 64 + lane];
            bf16x8 bl = WLf[(kk * 8 + nn) * 64 + lane];
            accA[nn] = MFMA16(a2[kk], bh, accA[nn]);
            accA[nn] = MFMA16(a2[kk], bl, accA[nn]);
        }
    }

    // ---- bias + ReLU + LayerNorm 2 (wave-internal) ----
#pragma unroll
    for (int nn = 0; nn < 8; ++nn) {
        float bv = lin1b[nn * 16 + mc];
#pragma unroll
        for (int reg = 0; reg < 4; ++reg)
            accA[nn][reg] = fmaxf(accA[nn][reg] + bv, 0.f);
    }
    float mu2[4], rs2[4];
#pragma unroll
    for (int reg = 0; reg < 4; ++reg) {
        float ps = 0.f, pq = 0.f;
#pragma unroll
        for (int nn = 0; nn < 8; ++nn) { float v = accA[nn][reg]; ps += v; pq += v * v; }
#pragma unroll
        for (int o = 1; o <= 8; o <<= 1) { ps += __shfl_xor(ps, o); pq += __shfl_xor(pq, o); }
        float m_ = ps * (1.f / NHID_);
        mu2[reg] = m_;
        rs2[reg] = rsqrtf(pq * (1.f / NHID_) - m_ * m_ + EPS_);
    }
#pragma unroll
    for (int nn = 0; nn < 8; ++nn) {
        int c = nn * 16 + mc;
        float gv = ln2g[c], bv = ln2b[c];
#pragma unroll
        for (int reg = 0; reg < 4; ++reg)
            zw[(q * 4 + reg) * ZPAD_ + c] =
                (bf16_t)((accA[nn][reg] - mu2[reg]) * rs2[reg] * gv + bv);
    }

    // ---- lin2: 16x128 @ 128x16(pad); accumulate into workspace accp ----
    f32x4 accO = {0.f, 0.f, 0.f, 0.f};
    const bf16x8* LHf = (const bf16x8*)L2h;
    const bf16x8* LLf = (const bf16x8*)L2l;
#pragma unroll
    for (int kk = 0; kk < 4; ++kk) {
        bf16x8 a3 = *(const bf16x8*)&zw[mc * ZPAD_ + kk * 32 + q * 8];
        accO = MFMA16(a3, LHf[kk * 64 + lane], accO);
        accO = MFMA16(a3, LLf[kk * 64 + lane], accO);
    }
    if (mc < NCLASS_) {
#pragma unroll
        for (int reg = 0; reg < 4; ++reg)
            atomicAdd(&accp[(b0 + q * 4 + reg) * NCLASS_ + mc], accO[reg]);
    }
}

// ---------------------------------------------------------------------------
// K3: out = accp/NFOREST + lin2_b
// ---------------------------------------------------------------------------
__global__ __launch_bounds__(256) void k_final(
    const float* __restrict__ accp, const float* __restrict__ lin2b,
    float* __restrict__ out)
{
    int i = blockIdx.x * 256 + threadIdx.x;
    if (i < B_ * NCLASS_) {
        int c = i % NCLASS_;
        out[i] = accp[i] * (1.f / NFOREST_) + lin2b[c];
    }
}

// ---------------------------------------------------------------------------
extern "C" void kernel_launch(void* const* d_in, const int* in_sizes, int n_in,
                              void* d_out, int out_size, void* d_ws, size_t ws_size,
                              hipStream_t stream)
{
    const float* x     = (const float*)d_in[0];
    const float* w1    = (const float*)d_in[1];
    const float* b1    = (const float*)d_in[2];
    const int*   perm  = (const int*)  d_in[3];
    const float* gn1g  = (const float*)d_in[4];
    const float* gn1b  = (const float*)d_in[5];
    const float* w2a   = (const float*)d_in[6];
    const float* b2a   = (const float*)d_in[7];
    const float* gn2g  = (const float*)d_in[8];
    const float* gn2b  = (const float*)d_in[9];
    const float* w2b   = (const float*)d_in[10];
    const float* b2b   = (const float*)d_in[11];
    const float* E     = (const float*)d_in[12];
    const int*   swr   = (const int*)  d_in[13];
    const float* ln1g  = (const float*)d_in[14];
    const float* ln1b  = (const float*)d_in[15];
    const float* lin1w = (const float*)d_in[16];
    const float* lin1b = (const float*)d_in[17];
    const float* ln2g  = (const float*)d_in[18];
    const float* ln2b  = (const float*)d_in[19];
    const float* lin2w = (const float*)d_in[20];
    const float* lin2b = (const float*)d_in[21];

    char* base = (char*)d_ws;
    bf16_t* w_t  = (bf16_t*)base;                                   // 2 MB
    float*  x_t  = (float*)(base + 2u * 1024 * 1024);               // 256 KB
    float*  accp = (float*)(base + 2u * 1024 * 1024 + 256 * 1024);  // 40 KB (64K slot)
    bf16_t* Eh   = (bf16_t*)(base + 2u * 1024 * 1024 + 256 * 1024 + 64 * 1024);
    bf16_t* El   = Eh  + (size_t)EG_FRAGS * 8;
    bf16_t* Wh   = El  + (size_t)EG_FRAGS * 8;
    bf16_t* Wl   = Wh  + (size_t)W1_FRAGS * 8;
    bf16_t* L2h  = Wl  + (size_t)W1_FRAGS * 8;
    bf16_t* L2l  = L2h + (size_t)L2_FRAGS * 8;

    float* outp = (float*)d_out;

    k_pre<<<296, 256, 0, stream>>>(x, x_t, accp);

    k_main<<<1833, 256, 0, stream>>>(E, swr, lin1w, lin2w,
                                     Eh, El, Wh, Wl, L2h, L2l,
                                     x_t, w1, b1, perm, gn1g, gn1b,
                                     w2a, b2a, gn2g, gn2b, w2b, b2b, w_t);

    k_forest<<<NFOREST_ * 16, 256, 0, stream>>>(
        w_t, swr, Eh, El, Wh, Wl, L2h, L2l,
        ln1g, ln1b, lin1b, ln2g, ln2b, accp);

    k_final<<<(B_ * NCLASS_ + 255) / 256, 256, 0, stream>>>(
        accp, lin2b, outp);
}